// Round 6
// baseline (288.538 us; speedup 1.0000x reference)
//
#include <hip/hip_runtime.h>
#include <math.h>

#define B_ROWS 4096
#define DIM    1024
#define NTOT   8192
#define NCLS   40
#define TILESG 64    // 8192 / 128
#define NBLKG  2080  // 64*65/2

typedef __attribute__((ext_vector_type(8))) short bf16x8;
typedef __attribute__((ext_vector_type(4))) float f32x4;

// ws layout (floats): [0]=nll_sum [1]=matdiff_sum [2]=sum_sq [3]=sxx [4]=syy
// [5]=smix(xy+yx) [6]=unused [7]=gram ticket counter ; [8..1032)=colsum[1024] ;
// [1032..9224)=sq[8192] ; byte 36896+ : bf16 total[8192*1024]
#define WS_TOT_BYTE_OFF 36896

#define MFMA16(d, x, y) d = __builtin_amdgcn_mfma_f32_16x16x32_bf16(x, y, d, 0, 0, 0)

__device__ __forceinline__ unsigned short f2bf(float f) {
  unsigned int u = __float_as_uint(f);
  u += 0x7fffu + ((u >> 16) & 1u);   // RNE
  return (unsigned short)(u >> 16);
}

__device__ __forceinline__ void async16(const void* g, void* l) {
  __builtin_amdgcn_global_load_lds(
      (const __attribute__((address_space(1))) unsigned int*)g,
      (__attribute__((address_space(3))) unsigned int*)l, 16, 0, 0);
}

__device__ __forceinline__ float wave_sum(float v) {
  v += __shfl_xor(v, 32);
  v += __shfl_xor(v, 16);
  v += __shfl_xor(v, 8);
  v += __shfl_xor(v, 4);
  v += __shfl_xor(v, 2);
  v += __shfl_xor(v, 1);
  return v;
}

__global__ void init_k(float* W) {
  int t = blockIdx.x * blockDim.x + threadIdx.x;
  if (t < 1032) W[t] = 0.f;   // scalars + ticket + colsum
}

// ---------------- fused pre: prep (256 blocks) + nll (16) + matdiff (1024) ---

__device__ void prep_body(int blk, const float* __restrict__ dense,
                          const float* __restrict__ sparse,
                          float* __restrict__ W,
                          unsigned short* __restrict__ tot) {
  float* colsum = W + 8;
  float* sq = W + 1032;
  const int t = threadIdx.x;
  const int lane = t & 63, wave = t >> 6;
  __shared__ float colsum_l[1024];
  __shared__ float w2r[4];
  #pragma unroll
  for (int x = 0; x < 4; ++x) colsum_l[t * 4 + x] = 0.f;

  float c[4][4];
  #pragma unroll
  for (int j = 0; j < 4; ++j)
    #pragma unroll
    for (int x = 0; x < 4; ++x) c[j][x] = 0.f;

  float rowtot = 0.f;
  const int rbase = blk * 32 + wave;   // 8 rows per wave, stride 4
  for (int i = 0; i < 8; ++i) {
    const int r = rbase + i * 4;
    const float* src = (r < B_ROWS) ? dense + (size_t)r * DIM
                                    : sparse + (size_t)(r - B_ROWS) * DIM;
    float sp = 0.f;
    #pragma unroll
    for (int j = 0; j < 4; ++j) {
      float4 v = ((const float4*)src)[lane + 64 * j];
      c[j][0] += v.x; c[j][1] += v.y; c[j][2] += v.z; c[j][3] += v.w;
      sp += v.x * v.x + v.y * v.y + v.z * v.z + v.w * v.w;
      ushort4 o;
      o.x = f2bf(v.x); o.y = f2bf(v.y); o.z = f2bf(v.z); o.w = f2bf(v.w);
      *(ushort4*)(tot + (size_t)r * DIM + (lane + 64 * j) * 4) = o;
    }
    sp = wave_sum(sp);
    if (lane == 0) { sq[r] = sp; rowtot += sp; }
  }
  if (lane == 0) w2r[wave] = rowtot;

  __syncthreads();
  #pragma unroll
  for (int j = 0; j < 4; ++j)
    #pragma unroll
    for (int x = 0; x < 4; ++x)
      atomicAdd(&colsum_l[4 * lane + 256 * j + x], c[j][x]);
  __syncthreads();
  #pragma unroll
  for (int x = 0; x < 4; ++x)
    atomicAdd(&colsum[t * 4 + x], colsum_l[t * 4 + x]);
  if (t == 0) atomicAdd(&W[2], w2r[0] + w2r[1] + w2r[2] + w2r[3]);
}

__device__ void nll_body(int blk, const float* __restrict__ pred,
                         const int* __restrict__ tgt, float* __restrict__ W) {
  const int i = blk * 256 + threadIdx.x;
  float v = pred[(size_t)i * NCLS + tgt[i]];
  v = wave_sum(v);
  __shared__ float red[4];
  if ((threadIdx.x & 63) == 0) red[threadIdx.x >> 6] = v;
  __syncthreads();
  if (threadIdx.x == 0) atomicAdd(&W[0], red[0] + red[1] + red[2] + red[3]);
}

__device__ void matdiff_body(int blk, const float* __restrict__ trans,
                             float* __restrict__ W) {
  const int t = threadIdx.x;
  const int lane = t & 63, wave = t >> 6;
  const int b = blk * 4 + wave;
  const float* Tb = trans + (size_t)b * 4096;
  const int fr = lane & 15;
  const int k8 = (lane >> 4) * 8;
  __shared__ float mred[4];
  bf16x8 frag[4][2];
  #pragma unroll
  for (int m = 0; m < 4; ++m) {
    #pragma unroll
    for (int kk = 0; kk < 2; ++kk) {
      const float* p = Tb + (size_t)(16 * m + fr) * 64 + kk * 32 + k8;
      float4 u0 = *(const float4*)p;
      float4 u1 = *(const float4*)(p + 4);
      bf16x8 f;
      f[0] = (short)f2bf(u0.x); f[1] = (short)f2bf(u0.y);
      f[2] = (short)f2bf(u0.z); f[3] = (short)f2bf(u0.w);
      f[4] = (short)f2bf(u1.x); f[5] = (short)f2bf(u1.y);
      f[6] = (short)f2bf(u1.z); f[7] = (short)f2bf(u1.w);
      frag[m][kk] = f;
    }
  }
  f32x4 acc[4][4];
  #pragma unroll
  for (int m = 0; m < 4; ++m)
    #pragma unroll
    for (int n = 0; n < 4; ++n) acc[m][n] = (f32x4)(0.f);
  #pragma unroll
  for (int kk = 0; kk < 2; ++kk)
    #pragma unroll
    for (int m = 0; m < 4; ++m)
      #pragma unroll
      for (int n = 0; n < 4; ++n)
        acc[m][n] = __builtin_amdgcn_mfma_f32_16x16x32_bf16(frag[m][kk], frag[n][kk],
                                                            acc[m][n], 0, 0, 0);
  float s = 0.f;
  const int crow = (lane >> 4) * 4;
  #pragma unroll
  for (int m = 0; m < 4; ++m)
    #pragma unroll
    for (int n = 0; n < 4; ++n)
      #pragma unroll
      for (int r = 0; r < 4; ++r) {
        int grow = 16 * m + crow + r;
        int gcol = 16 * n + fr;
        float g = acc[m][n][r];
        float d = (grow == gcol) ? (1.f - g) : (-g);
        s += d * d;
      }
  s = wave_sum(s);
  if (lane == 0) mred[wave] = sqrtf(s);
  __syncthreads();
  if (t == 0) atomicAdd(&W[1], mred[0] + mred[1] + mred[2] + mred[3]);
}

__global__ __launch_bounds__(256) void fused_pre_k(
    const float* __restrict__ pred, const int* __restrict__ tgt,
    const float* __restrict__ trans, const float* __restrict__ dense,
    const float* __restrict__ sparse, float* __restrict__ W,
    unsigned short* __restrict__ tot) {
  const int blk = blockIdx.x;
  if (blk < 256)       prep_body(blk, dense, sparse, W, tot);
  else if (blk < 272)  nll_body(blk - 256, pred, tgt, W);
  else                 matdiff_body(blk - 272, trans, W);
}

// ---------------- gram: 128x128 tiles, 4 waves (2Mx2N), BK=64, single-buffer --
// m97 structure (874-TF-proven): plain 2-barrier K-loop, NO asm waits, NO
// setprio; latency hiding comes from 4 co-resident blocks/CU (33KB LDS,
// <=128 VGPR) overlapping each other's stage/compute phases (m114 mechanism).
// T2 XOR-swizzle (rule #21: linear LDS dest + inverse-swizzled global source +
// swizzled read; r1-verified 0 conflicts, absmax 0).  T1 XCD chunking.
__global__ __launch_bounds__(256, 4) void gram_k(const unsigned short* __restrict__ tot,
                                                 float* __restrict__ W,
                                                 float* __restrict__ out) {
  __shared__ short As[128 * 64];   // [128 rows][64 k] shorts, 128B rows
  __shared__ short Bs[128 * 64];
  __shared__ float sqA[128], sqB[128], red[4];
  const float* sq = W + 1032;
  const float* colsum = W + 8;
  const int t = threadIdx.x;              // 0..255
  const int lane = t & 63, wave = t >> 6; // 4 waves
  const int wr = wave >> 1, wc = wave & 1;

  // T1: XCD-contiguous remap; 2080 = 8*260 -> chunking bijective
  int p = (blockIdx.x & 7) * (NBLKG / 8) + (blockIdx.x >> 3);

  // decode linear id -> (bi, bj), bi <= bj, T=64
  int bi = (int)((2 * TILESG + 1 -
                  sqrtf((float)((2 * TILESG + 1) * (2 * TILESG + 1) - 8 * p))) * 0.5f);
  if (bi < 0) bi = 0;
  if (bi >= TILESG) bi = TILESG - 1;
  int start = bi * (2 * TILESG - bi + 1) / 2;
  while (p < start) { --bi; start = bi * (2 * TILESG - bi + 1) / 2; }
  while (p >= start + (TILESG - bi)) { start += TILESG - bi; ++bi; }
  const int bj = bi + (p - start);

  // staging (r1-verified): chunk = c4*256+t ; row = chunk>>3 ;
  // seg' = (chunk&7)^(row&7) ; LDS dest linear at chunk*16B
  const unsigned short* pA[4];
  const unsigned short* pB[4];
  int loff[4];
  #pragma unroll
  for (int c4 = 0; c4 < 4; ++c4) {
    int chunk = c4 * 256 + t;
    int row = chunk >> 3;
    int segp = (chunk & 7) ^ (row & 7);
    pA[c4] = tot + (size_t)(bi * 128 + row) * DIM + segp * 8;
    pB[c4] = tot + (size_t)(bj * 128 + row) * DIM + segp * 8;
    loff[c4] = chunk * 8;
  }

  // stage K-tile 0
  #pragma unroll
  for (int c4 = 0; c4 < 4; ++c4) {
    async16(pA[c4], &As[loff[c4]]);
    async16(pB[c4], &Bs[loff[c4]]);
  }

  // overlap with load latency: sq staging + per-block bandwidth coefficient
  if (t < 128) sqA[t] = sq[bi * 128 + t];
  else         sqB[t - 128] = sq[bj * 128 + (t - 128)];
  float csp = 0.f;
  #pragma unroll
  for (int j = 0; j < 16; ++j) { float v = colsum[lane + 64 * j]; csp += v * v; }
  csp = wave_sum(csp);
  double sumdots = (double)csp;
  double sum_sq = (double)W[2];
  double sumL2 = 2.0 * (double)NTOT * sum_sq - 2.0 * sumdots;
  double bwv = sumL2 / ((double)NTOT * (double)NTOT - (double)NTOT);
  const float cexp16 = (float)(4.0 / bwv) * 0.0625f;  // c/16: widest kernel coeff

  f32x4 acc[4][4];
  #pragma unroll
  for (int m = 0; m < 4; ++m)
    #pragma unroll
    for (int n = 0; n < 4; ++n) acc[m][n] = (f32x4)(0.f);

  // swizzled read: byte within 128B row = colb ^ ((fr&7)<<4);
  // all fragment rows have row&7 == fr&7 (wr*64, 16m multiples of 8)
  const int q = lane >> 4;
  const int fr = lane & 15;
  const int swz = (fr & 7) << 4;

  __syncthreads();   // compiler drains vmcnt before barrier: tile 0 in LDS

  for (int kt = 0; kt < 16; ++kt) {
    #pragma unroll
    for (int kk = 0; kk < 2; ++kk) {
      const int cswz = (kk * 64 + q * 16) ^ swz;
      bf16x8 a[4], b[4];
      #pragma unroll
      for (int m = 0; m < 4; ++m)
        a[m] = *(const bf16x8*)((const char*)As + (wr * 64 + 16 * m + fr) * 128 + cswz);
      #pragma unroll
      for (int n = 0; n < 4; ++n)
        b[n] = *(const bf16x8*)((const char*)Bs + (wc * 64 + 16 * n + fr) * 128 + cswz);
      #pragma unroll
      for (int m = 0; m < 4; ++m)
        #pragma unroll
        for (int n = 0; n < 4; ++n) MFMA16(acc[m][n], a[m], b[n]);
    }
    if (kt < 15) {
      __syncthreads();   // all waves done reading this tile
      #pragma unroll
      for (int c4 = 0; c4 < 4; ++c4) {
        async16(pA[c4] + (kt + 1) * 64, &As[loff[c4]]);
        async16(pB[c4] + (kt + 1) * 64, &Bs[loff[c4]]);
      }
      __syncthreads();   // vmcnt(0) drain before barrier: next tile landed
    }
  }

  // epilogue: l2 -> 5-kernel sum. k_i = exp(-l2*c/2^i); exp of smallest,
  // then 4 squarings
  float s = 0.f;
  const int crow = (lane >> 4) * 4;
  #pragma unroll
  for (int m = 0; m < 4; ++m) {
    #pragma unroll
    for (int n = 0; n < 4; ++n) {
      #pragma unroll
      for (int r = 0; r < 4; ++r) {
        int il = wr * 64 + 16 * m + crow + r;
        int jl = wc * 64 + 16 * n + fr;
        float l2 = sqA[il] + sqB[jl] - 2.f * acc[m][n][r];
        l2 = fmaxf(l2, 0.f);
        float k4 = __expf(-l2 * cexp16);
        float k3 = k4 * k4;
        float k2 = k3 * k3;
        float k1 = k2 * k2;
        float k0 = k1 * k1;
        s += k0 + k1 + k2 + k3 + k4;
      }
    }
  }
  s = wave_sum(s);
  if (lane == 0) red[wave] = s;
  __syncthreads();
  if (t == 0) {
    float ts = red[0] + red[1] + red[2] + red[3];
    int idx; float wgt;
    if (bi == bj)      { idx = (bi < 32) ? 3 : 4; wgt = 1.f; }
    else if (bj < 32)  { idx = 3; wgt = 2.f; }
    else if (bi >= 32) { idx = 4; wgt = 2.f; }
    else               { idx = 5; wgt = 2.f; }
    atomicAdd(&W[idx], wgt * ts);
    __threadfence();
    unsigned int tk = atomicAdd((unsigned int*)(W + 7), 1u);
    if (tk == NBLKG - 1) {   // last block: final combine
      __threadfence();
      float nll = -*(volatile float*)(W + 0) / (float)B_ROWS;
      float mat =  *(volatile float*)(W + 1) / (float)B_ROWS;
      float sxx =  *(volatile float*)(W + 3);
      float syy =  *(volatile float*)(W + 4);
      float smx =  *(volatile float*)(W + 5);
      float mmd = (sxx + syy - smx) / ((float)B_ROWS * (float)B_ROWS);
      out[0] = 0.1f * nll + 0.001f * mat + 0.5f * mmd;
    }
  }
}

extern "C" void kernel_launch(void* const* d_in, const int* in_sizes, int n_in,
                              void* d_out, int out_size, void* d_ws, size_t ws_size,
                              hipStream_t stream) {
  const float* pred   = (const float*)d_in[0];
  const int*   tgt    = (const int*)d_in[1];
  const float* trans  = (const float*)d_in[2];
  const float* dense  = (const float*)d_in[3];
  const float* sparse = (const float*)d_in[4];
  float* W = (float*)d_ws;
  unsigned short* tot = (unsigned short*)((char*)d_ws + WS_TOT_BYTE_OFF);
  float* out = (float*)d_out;

  init_k<<<dim3(5), dim3(256), 0, stream>>>(W);
  fused_pre_k<<<dim3(1296), dim3(256), 0, stream>>>(pred, tgt, trans, dense, sparse, W, tot);
  gram_k<<<dim3(NBLKG), dim3(256), 0, stream>>>(tot, W, out);
}